// Round 2
// baseline (685.763 us; speedup 1.0000x reference)
//
#include <hip/hip_runtime.h>
#include <stdint.h>

#define F_IN 512
#define F_OUT 16

// ---------------- K1: in-degree histogram over dst (edge_index is int32!) ----------------
__global__ void k_hist(const int* __restrict__ ei, int E, int* __restrict__ hist) {
    int i = blockIdx.x * blockDim.x + threadIdx.x;
    int stride = gridDim.x * blockDim.x;
    for (int e = i; e < E; e += stride) {
        int d = ei[(size_t)E + e];
        atomicAdd(&hist[d], 1);
    }
}

// ---------------- K2: dinv = rsqrt(deg) with self-loop ----------------
__global__ void k_dinv(const int* __restrict__ hist, float* __restrict__ dinv, int N) {
    int n = blockIdx.x * blockDim.x + threadIdx.x;
    if (n < N) dinv[n] = rsqrtf((float)(hist[n] + 1));
}

// ---------------- K3a: per-block sums of hist ----------------
__global__ void k_scan_partial(const int* __restrict__ hist, int N, int* __restrict__ blocksum) {
    __shared__ int sm[256];
    int n = blockIdx.x * 256 + threadIdx.x;
    int v = (n < N) ? hist[n] : 0;
    sm[threadIdx.x] = v;
    __syncthreads();
    for (int s = 128; s > 0; s >>= 1) {
        if (threadIdx.x < s) sm[threadIdx.x] += sm[threadIdx.x + s];
        __syncthreads();
    }
    if (threadIdx.x == 0) blocksum[blockIdx.x] = sm[0];
}

// ---------------- K3b: exclusive scan of block sums (single block, up to 1024) ----------------
__global__ void k_scan_block(const int* __restrict__ blocksum, int NB, int* __restrict__ blockoff) {
    __shared__ int sm[1024];
    int t = threadIdx.x;
    int v = (t < NB) ? blocksum[t] : 0;
    sm[t] = v;
    __syncthreads();
    for (int s = 1; s < 1024; s <<= 1) {
        int add = (t >= s) ? sm[t - s] : 0;
        __syncthreads();
        sm[t] += add;
        __syncthreads();
    }
    if (t < NB) blockoff[t] = sm[t] - v;  // exclusive
}

// ---------------- K3c: final offsets = blockoff + intra-block exclusive scan ----------------
__global__ void k_scan_final(const int* __restrict__ hist, int N, const int* __restrict__ blockoff,
                             int* __restrict__ offsets, int* __restrict__ cursor) {
    __shared__ int sm[256];
    int t = threadIdx.x;
    int n = blockIdx.x * 256 + t;
    int v = (n < N) ? hist[n] : 0;
    sm[t] = v;
    __syncthreads();
    for (int s = 1; s < 256; s <<= 1) {
        int add = (t >= s) ? sm[t - s] : 0;
        __syncthreads();
        sm[t] += add;
        __syncthreads();
    }
    if (n < N) {
        int off = blockoff[blockIdx.x] + sm[t] - v;
        offsets[n] = off;
        cursor[n] = off;
    }
}

// ---------------- K4: scatter edges into CSR (src only) bucketed by dst ----------------
__global__ void k_scatter(const int* __restrict__ ei, int E,
                          int* __restrict__ cursor, int* __restrict__ csr) {
    int i = blockIdx.x * blockDim.x + threadIdx.x;
    int stride = gridDim.x * blockDim.x;
    for (int e = i; e < E; e += stride) {
        int s = ei[e];
        int d = ei[(size_t)E + e];
        int pos = atomicAdd(&cursor[d], 1);
        csr[pos] = s;
    }
}

// ---------------- K5: xw1' = dinv[n] * (x @ W1) ----------------
// block = 256 threads = 4 waves; each wave: 4 node-groups of 16 j-lanes.
__global__ __launch_bounds__(256) void k_gemm1(const float* __restrict__ x, const float* __restrict__ W1,
                                               const float* __restrict__ dinv, float* __restrict__ xw1p, int N) {
    __shared__ float Wt[16 * 516];  // W1 transposed, pad stride 516 -> ~2-way conflicts (free)
    for (int idx = threadIdx.x; idx < F_IN * F_OUT; idx += 256) {
        int k = idx >> 4, j = idx & 15;
        Wt[j * 516 + k] = W1[idx];
    }
    __syncthreads();

    int lane = threadIdx.x & 63;
    int wave = threadIdx.x >> 6;
    int grp  = lane >> 4;
    int j    = lane & 15;
    int node = blockIdx.x * 16 + wave * 4 + grp;
    if (node >= N) return;

    const float4* xr = (const float4*)(x + (size_t)node * F_IN);
    const float4* wr = (const float4*)(Wt + j * 516);
    float acc = 0.0f;
#pragma unroll 4
    for (int kk = 0; kk < F_IN / 4; kk++) {
        float4 xv = xr[kk];
        float4 wv = wr[kk];
        acc += xv.x * wv.x + xv.y * wv.y + xv.z * wv.z + xv.w * wv.w;
    }
    xw1p[(size_t)node * F_OUT + j] = dinv[node] * acc;
}

// ---------------- K6: agg1 + bias + ReLU + fused (h @ W2) * dinv ----------------
__global__ __launch_bounds__(256) void k_agg1(const float* __restrict__ xw, const int* __restrict__ offsets,
                                              const int* __restrict__ hist, const float* __restrict__ dinv,
                                              const int* __restrict__ csr, const float* __restrict__ b1,
                                              const float* __restrict__ W2, float* __restrict__ xw2p, int N) {
    __shared__ float W2s[256];
    if (threadIdx.x < 256) W2s[threadIdx.x] = W2[threadIdx.x];
    __syncthreads();

    int lane = threadIdx.x & 63;
    int wave = threadIdx.x >> 6;
    int grp  = lane >> 4;
    int j    = lane & 15;
    int node = blockIdx.x * 16 + wave * 4 + grp;
    if (node >= N) return;

    float dn = dinv[node];
    float acc = xw[(size_t)node * F_OUT + j];  // self-loop term (pre-scaled by dinv at producer)
    float acc2 = 0.0f;
    int start = offsets[node], cnt = hist[node];
    int i = 0;
    for (; i + 2 <= cnt; i += 2) {
        int s0 = csr[start + i];
        int s1 = csr[start + i + 1];
        acc  += xw[(size_t)s0 * F_OUT + j];
        acc2 += xw[(size_t)s1 * F_OUT + j];
    }
    if (i < cnt) acc += xw[(size_t)csr[start + i] * F_OUT + j];

    float h = fmaxf(dn * (acc + acc2) + b1[j], 0.0f);

    // fused 16x16 GEMM: xw2'[n][j] = dinv[n] * sum_r h[r] * W2[r][j]
    float o = 0.0f;
    int base = lane & 48;  // group base within wave
#pragma unroll
    for (int r = 0; r < 16; r++) {
        float hr = __shfl(h, base + r);
        o += hr * W2s[r * 16 + j];
    }
    xw2p[(size_t)node * F_OUT + j] = dn * o;
}

// ---------------- K7: agg2 + bias + ReLU + fused mean-pool partials ----------------
__global__ __launch_bounds__(256) void k_agg2(const float* __restrict__ xw, const int* __restrict__ offsets,
                                              const int* __restrict__ hist, const float* __restrict__ dinv,
                                              const int* __restrict__ csr, const float* __restrict__ b2,
                                              float* __restrict__ partials, int N) {
    int lane = threadIdx.x & 63;
    int wave = threadIdx.x >> 6;
    int grp  = lane >> 4;
    int j    = lane & 15;
    int node = blockIdx.x * 16 + wave * 4 + grp;

    float r = 0.0f;
    if (node < N) {
        float dn = dinv[node];
        float acc = xw[(size_t)node * F_OUT + j];
        float acc2 = 0.0f;
        int start = offsets[node], cnt = hist[node];
        int i = 0;
        for (; i + 2 <= cnt; i += 2) {
            int s0 = csr[start + i];
            int s1 = csr[start + i + 1];
            acc  += xw[(size_t)s0 * F_OUT + j];
            acc2 += xw[(size_t)s1 * F_OUT + j];
        }
        if (i < cnt) acc += xw[(size_t)csr[start + i] * F_OUT + j];
        r = fmaxf(dn * (acc + acc2) + b2[j], 0.0f);
    }
    // reduce 4 node-groups within the wave: lanes j, j+16, j+32, j+48
    r += __shfl_xor(r, 16);
    r += __shfl_xor(r, 32);
    __shared__ float sm[4][16];
    if (lane < 16) sm[wave][j] = r;
    __syncthreads();
    if (threadIdx.x < 16) {
        float s = sm[0][threadIdx.x] + sm[1][threadIdx.x] + sm[2][threadIdx.x] + sm[3][threadIdx.x];
        partials[(size_t)blockIdx.x * 16 + threadIdx.x] = s;
    }
}

// ---------------- K8: final reduce + fc ----------------
__global__ void k_final(const float* __restrict__ partials, int NB, const float* __restrict__ fc_w,
                        const float* __restrict__ fc_b, float* __restrict__ out, float invN) {
    __shared__ float sm[64][16];
    int t = threadIdx.x;  // 1024 threads
    int g = t >> 4, j = t & 15;
    float s = 0.0f;
    for (int bk = g; bk < NB; bk += 64) s += partials[(size_t)bk * 16 + j];
    sm[g][j] = s;
    __syncthreads();
    for (int str = 32; str > 0; str >>= 1) {
        if (g < str) sm[g][j] += sm[g + str][j];
        __syncthreads();
    }
    if (t == 0) {
        float acc = fc_b[0];
#pragma unroll
        for (int jj = 0; jj < 16; jj++) acc += sm[0][jj] * invN * fc_w[jj];
        out[0] = acc;
    }
}

extern "C" void kernel_launch(void* const* d_in, const int* in_sizes, int n_in,
                              void* d_out, int out_size, void* d_ws, size_t ws_size,
                              hipStream_t stream) {
    const float* x   = (const float*)d_in[0];
    const int*   ei  = (const int*)d_in[1];   // harness delivers integer inputs as int32
    const float* W1  = (const float*)d_in[2];
    const float* b1  = (const float*)d_in[3];
    const float* W2  = (const float*)d_in[4];
    const float* b2  = (const float*)d_in[5];
    const float* fcw = (const float*)d_in[6];
    const float* fcb = (const float*)d_in[7];
    float* out = (float*)d_out;

    int N = in_sizes[0] / F_IN;   // 100000
    int E = in_sizes[1] / 2;      // 3200000

    // ---- workspace carve-up (256B aligned), total ~27.5 MB ----
    char* p = (char*)d_ws;
    auto alloc = [&](size_t bytes) {
        void* r = (void*)p;
        p += (bytes + 255) & ~(size_t)255;
        return r;
    };
    int*   hist     = (int*)alloc((size_t)N * 4);
    int*   offsets  = (int*)alloc((size_t)N * 4);
    int*   cursor   = (int*)alloc((size_t)N * 4);
    float* dinv     = (float*)alloc((size_t)N * 4);
    int*   blocksum = (int*)alloc(1024 * 4);
    int*   blockoff = (int*)alloc(1024 * 4);
    int*   csr      = (int*)alloc((size_t)E * 4);
    float* xw1p     = (float*)alloc((size_t)N * F_OUT * 4);
    float* xw2p     = (float*)alloc((size_t)N * F_OUT * 4);
    int NB_NODE = (N + 15) / 16;              // 6250
    float* partials = (float*)alloc((size_t)NB_NODE * 16 * 4);

    int NBC = (N + 255) / 256;                // 391 scan chunks

    hipMemsetAsync(hist, 0, (size_t)N * 4, stream);

    k_hist<<<2048, 256, 0, stream>>>(ei, E, hist);
    k_dinv<<<(N + 255) / 256, 256, 0, stream>>>(hist, dinv, N);
    k_scan_partial<<<NBC, 256, 0, stream>>>(hist, N, blocksum);
    k_scan_block<<<1, 1024, 0, stream>>>(blocksum, NBC, blockoff);
    k_scan_final<<<NBC, 256, 0, stream>>>(hist, N, blockoff, offsets, cursor);
    k_scatter<<<2048, 256, 0, stream>>>(ei, E, cursor, csr);

    k_gemm1<<<NB_NODE, 256, 0, stream>>>(x, W1, dinv, xw1p, N);
    k_agg1<<<NB_NODE, 256, 0, stream>>>(xw1p, offsets, hist, dinv, csr, b1, W2, xw2p, N);
    k_agg2<<<NB_NODE, 256, 0, stream>>>(xw2p, offsets, hist, dinv, csr, b2, partials, N);
    k_final<<<1, 1024, 0, stream>>>(partials, NB_NODE, fcw, fcb, out, 1.0f / (float)N);
}